// Round 12
// baseline (445.381 us; speedup 1.0000x reference)
//
#include <hip/hip_runtime.h>
#include <math.h>

// Problem constants
#define B_   64
#define T_   256
#define W_   20
#define NP_  6
#define NT_  12
#define CC_  32      // CONV_CH
#define FD_  8       // FRAG_DIM
#define PR_  64      // PROJ

typedef float v2f __attribute__((ext_vector_type(2)));
typedef float v4f __attribute__((ext_vector_type(4)));
typedef _Float16 half2_t __attribute__((ext_vector_type(2)));
typedef _Float16 v4h __attribute__((ext_vector_type(4)));
typedef _Float16 v8h __attribute__((ext_vector_type(8)));

// Wave-local LDS ordering: drain LDS ops only; no vmcnt, no barrier.
#define WAVE_SYNC() asm volatile("s_waitcnt lgkmcnt(0)" ::: "memory")
// Cross-wave barrier WITHOUT vmem drain (R7-proven with 4 waves).
#define LDS_BARRIER() asm volatile("s_waitcnt lgkmcnt(0)\n\ts_barrier" ::: "memory")

#define H2(u) __builtin_bit_cast(half2_t, (u))

__device__ __forceinline__ unsigned packh2(float a, float b) {
    union { _Float16 h[2]; unsigned u; } cv;
    cv.h[0] = (_Float16)a; cv.h[1] = (_Float16)b;
    return cv.u;
}

// Fast activations via v_rcp_f32 (R11-proven).
__device__ __forceinline__ float sigmoidf_(float x) {
    return __builtin_amdgcn_rcpf(1.0f + __expf(-x));
}
__device__ __forceinline__ float tanhf_(float x) {
    x = fminf(fmaxf(x, -15.0f), 15.0f);
    float e = __expf(2.0f * x);
    return (e - 1.0f) * __builtin_amdgcn_rcpf(e + 1.0f);
}

// -------------------------------------------------------------------------
// Kernel 1: encoders + projection + LSTM input-gate precompute.
// Only change this round: xg stored in MFMA C-fragment order
//   idx(t,g,b) = (((t*16 + (g>>4))*4 + ((g>>2)&3))*64 + b)*4 + (g&3)
// so the LSTM can float4-load its C-init fragments directly.
// -------------------------------------------------------------------------
__global__ __launch_bounds__(256, 4) void encoder_kernel(
    const float* __restrict__ pressure, const float* __restrict__ torque,
    const float* __restrict__ frag,
    const float* __restrict__ pw1, const float* __restrict__ pb1,
    const float* __restrict__ pw2, const float* __restrict__ pb2,
    const float* __restrict__ tw1, const float* __restrict__ tb1,
    const float* __restrict__ tw2, const float* __restrict__ tb2,
    const float* __restrict__ fw,  const float* __restrict__ fb,
    const float* __restrict__ prw, const float* __restrict__ prb,
    const float* __restrict__ Wih, const float* __restrict__ bih,
    const float* __restrict__ bhh,
    float* __restrict__ xg)             // C-fragment order, 16 MB
{
    const int tid  = threadIdx.x;       // 0..255
    const int wv   = tid >> 6;          // wave 0..3
    const int lane = tid & 63;
    const int bt   = blockIdx.x * 4 + wv;   // window id
    const int b    = bt >> 8;
    const int t    = bt & 255;
    const int  o   = lane & 31;
    const bool isp = lane < 32;
    const int  s   = isp ? 0 : 1;       // stream: 0=pressure, 1=torque

    __shared__ unsigned w2p[64 * 49];                    // 12544 B packed conv2 wts
    __shared__ __align__(16) unsigned xwp[4][2][120];    //  3840 B
    __shared__ __align__(16) unsigned h1p[4][2][320];    // 10240 B
    __shared__ __align__(16) float catb4[4][72];
    __shared__ __align__(16) float featsh4[4][64];

    float* catb   = catb4[wv];
    float* featsh = featsh4[wv];

    // ---- stage conv2 weights once per block, packed f16 pairs ----
    for (int idx = tid; idx < 64 * 48; idx += 256) {
        int r = idx / 48, c = idx - r * 48;
        int m = c / 3, k = c - m * 3;
        const float* src = (r < 32) ? (pw2 + r * 96) : (tw2 + (r - 32) * 96);
        w2p[r * 49 + c] = packh2(src[(2 * m) * 3 + k], src[(2 * m + 1) * 3 + k]);
    }

    // ---- zero + stage own window as packed f16 pairs (transposed) ----
    {
        unsigned* xz = &xwp[wv][0][0];
        #pragma unroll
        for (int idx = lane; idx < 240; idx += 64) xz[idx] = 0;
    }
    const float* pin = pressure + (size_t)bt * (W_ * NP_);
    for (int idx = lane; idx < W_ * NP_; idx += 64) {
        int w = idx / NP_, i = idx - w * NP_;
        ((_Float16*)&xwp[wv][0][(i >> 1) * 20 + w])[i & 1] = (_Float16)pin[idx];
    }
    const float* tin = torque + (size_t)bt * (W_ * NT_);
    for (int idx = lane; idx < W_ * NT_; idx += 64) {
        int w = idx / NT_, i = idx - w * NT_;
        ((_Float16*)&xwp[wv][1][(i >> 1) * 20 + w])[i & 1] = (_Float16)tin[idx];
    }
    if (lane < FD_) catb[64 + lane] = fmaxf(frag[b] * fw[lane] + fb[lane], 0.0f);

    // ---- conv1 weights: packed f16 pairs in regs, zero-padded to 6 pairs ----
    unsigned w1p[18];
    {
        const float* w1 = isp ? (pw1 + o * (NP_ * 3)) : (tw1 + o * (NT_ * 3));
        const int npr = isp ? 3 : 6;
        #pragma unroll
        for (int m = 0; m < 6; ++m)
            #pragma unroll
            for (int k = 0; k < 3; ++k)
                w1p[m * 3 + k] = (m < npr)
                    ? packh2(w1[(2 * m) * 3 + k], w1[(2 * m + 1) * 3 + k])
                    : 0u;
    }
    const float bz1 = isp ? pb1[o] : tb1[o];
    const float bz2 = isp ? pb2[o] : tb2[o];
    WAVE_SYNC();

    // ---- conv1: 6 pair-rows x 3 taps x 18 pos, dot2 f16 -> f32 acc ----
    {
        const unsigned* xr = &xwp[wv][s][0];
        float acc[18];
        #pragma unroll
        for (int l = 0; l < 18; ++l) acc[l] = bz1;
        #pragma unroll
        for (int m = 0; m < 6; ++m) {
            uint4 r4[5];
            const uint4* rp = (const uint4*)(xr + m * 20);
            #pragma unroll
            for (int q = 0; q < 5; ++q) r4[q] = rp[q];
            const unsigned* rw = (const unsigned*)r4;
            const half2_t wk0 = H2(w1p[m * 3]), wk1 = H2(w1p[m * 3 + 1]), wk2 = H2(w1p[m * 3 + 2]);
            #pragma unroll
            for (int l = 0; l < 18; ++l) {
                float a = acc[l];
                a = __builtin_amdgcn_fdot2(wk0, H2(rw[l]),     a, false);
                a = __builtin_amdgcn_fdot2(wk1, H2(rw[l + 1]), a, false);
                a = __builtin_amdgcn_fdot2(wk2, H2(rw[l + 2]), a, false);
                acc[l] = a;
            }
        }
        #pragma unroll
        for (int l = 0; l < 18; ++l)
            ((_Float16*)&h1p[wv][s][(o >> 1) * 20 + l])[o & 1] = (_Float16)fmaxf(acc[l], 0.0f);
    }
    __syncthreads();   // the ONE real barrier: w2p (cross-wave) + h1p ready

    // ---- conv2: 16 pair-rows x 3 taps x 16 pos, weights from LDS ----
    {
        const unsigned* hr   = &h1p[wv][s][0];
        const unsigned* wrow = w2p + lane * 49;
        float sacc[16];
        #pragma unroll
        for (int l = 0; l < 16; ++l) sacc[l] = bz2;
        #pragma unroll 4
        for (int m = 0; m < 16; ++m) {
            uint4 r4[5];
            const uint4* rp = (const uint4*)(hr + m * 20);
            #pragma unroll
            for (int q = 0; q < 5; ++q) r4[q] = rp[q];
            const unsigned* rw = (const unsigned*)r4;
            const half2_t wk0 = H2(wrow[m * 3]), wk1 = H2(wrow[m * 3 + 1]), wk2 = H2(wrow[m * 3 + 2]);
            #pragma unroll
            for (int l = 0; l < 16; ++l) {
                float a = sacc[l];
                a = __builtin_amdgcn_fdot2(wk0, H2(rw[l]),     a, false);
                a = __builtin_amdgcn_fdot2(wk1, H2(rw[l + 1]), a, false);
                a = __builtin_amdgcn_fdot2(wk2, H2(rw[l + 2]), a, false);
                sacc[l] = a;
            }
        }
        float m2 = 0.0f;
        #pragma unroll
        for (int l = 0; l < 16; ++l) m2 += fmaxf(sacc[l], 0.0f);
        catb[lane] = m2 * 0.0625f;
    }
    WAVE_SYNC();

    // ---- projection 72 -> 64, relu (f32) ----
    {
        float acc = prb[lane];
        const float4* w4 = (const float4*)(prw + lane * 72);
        const float4* c4 = (const float4*)catb;
        #pragma unroll
        for (int q = 0; q < 18; ++q) {
            float4 w = w4[q], cv = c4[q];
            acc += w.x * cv.x + w.y * cv.y + w.z * cv.z + w.w * cv.w;
        }
        featsh[lane] = fmaxf(acc, 0.0f);
    }
    WAVE_SYNC();

    // ---- xg = feat @ Wih.T + bih + bhh ; MFMA C-fragment order stores ----
    {
        float4 fr[16];
        const float4* f4 = (const float4*)featsh;
        #pragma unroll
        for (int q = 0; q < 16; ++q) fr[q] = f4[q];
        #pragma unroll
        for (int gi = 0; gi < 4; ++gi) {
            const int g = gi * 64 + lane;        // torch gate order i,f,g,o
            const float4* w4 = (const float4*)(Wih + (size_t)g * 64);
            float acc = bih[g] + bhh[g];
            #pragma unroll
            for (int q = 0; q < 16; ++q) {
                float4 w = w4[q];
                acc += w.x * fr[q].x + w.y * fr[q].y + w.z * fr[q].z + w.w * fr[q].w;
            }
            const int mt   = g >> 4;             // M-tile (16 gates each)
            const int quad = (g >> 2) & 3;       // row-quad within tile
            const int reg  = g & 3;              // reg within quad
            xg[(size_t)(((t * 16 + mt) * 4 + quad) * 64 + b) * 4 + reg] = acc;
        }
    }
}

// -------------------------------------------------------------------------
// Kernel 2: LSTM as batched MFMA GEMM. 4 blocks x 256 threads (4 waves);
// block nb handles batches [nb*16, nb*16+16).
// Per step: G(256x16) = Whh(256x64) . H^T(64x16) + Xg  via 16x16x32 f16 MFMA.
//   A = Whh (STATIC f16 fragments, loaded once: no weight traffic in loop).
//   Wave u owns M-tiles {u,4+u,8+u,12+u} -> each lane holds i,f,g,o for
//   4 units x 1 batch in C layout (col=lane&15=batch, row=quad*4+reg=gate)
//   -> cell update is lane-local, c lives in VGPRs forever.
//   B = H^T from LDS ping-pong (f16), 2 x ds_read_b128 per step.
//   One LDS_BARRIER per step (no vmcnt drain); xg C-init prefetched 2 deep.
// -------------------------------------------------------------------------
__global__ __launch_bounds__(256, 1) void lstm_kernel(
    const float* __restrict__ xg,     // C-fragment order (see encoder)
    const float* __restrict__ Whh,    // (256,64) f32
    float* __restrict__ hout,         // (B,T,64) f32
    float* __restrict__ dout)         // full output buffer
{
    const int nb   = blockIdx.x;      // batch group
    const int tid  = threadIdx.x;
    const int u    = tid >> 6;        // wave = unit group
    const int lane = tid & 63;
    const int bL   = lane & 15;       // C col / B n (batch-local)
    const int quad = lane >> 4;

    __shared__ __align__(16) _Float16 Hl[2][16][72];   // [buf][batch][unit], 16B-aligned rows

    // ---- A fragments: Whh rows as f16, 4 gate-types x 2 K-chunks ----
    // A mapping: A[m=lane&15][k=quad*8+j] (guide-verified for 16x16x32)
    v8h A[4][2];
    #pragma unroll
    for (int gt = 0; gt < 4; ++gt) {
        const int grow = gt * 64 + u * 16 + (lane & 15);
        #pragma unroll
        for (int kc = 0; kc < 2; ++kc) {
            const float* wp = Whh + (size_t)grow * 64 + kc * 32 + quad * 8;
            v8h a;
            #pragma unroll
            for (int jj = 0; jj < 8; ++jj) a[jj] = (_Float16)wp[jj];
            A[gt][kc] = a;
        }
    }

    // zero H buffers
    for (int i = tid; i < 2 * 16 * 72 / 2; i += 256) ((unsigned*)Hl)[i] = 0u;
    v4f c4 = {0.0f, 0.0f, 0.0f, 0.0f};
    v4f h4 = {0.0f, 0.0f, 0.0f, 0.0f};
    __syncthreads();

    const int b = nb * 16 + bL;       // this lane's batch (C col)
    // xg float4 index: t*4096 + ((mt*4)+quad)*64 + b, mt = gt*4+u
    const v4f* xg4 = (const v4f*)xg;
    int off[4];
    #pragma unroll
    for (int gt = 0; gt < 4; ++gt) off[gt] = (((gt * 4 + u) * 4) + quad) * 64 + b;

    // 2-deep ring prefetch of C-init fragments
    v4f x0[4], x1[4];
    #pragma unroll
    for (int gt = 0; gt < 4; ++gt) x0[gt] = xg4[off[gt]];
    #pragma unroll
    for (int gt = 0; gt < 4; ++gt) x1[gt] = xg4[4096 + off[gt]];

    float* hbase = hout + ((size_t)b * T_) * 64 + u * 16 + quad * 4;

    for (int t = 0; t < T_; ++t) {
        const int tp = (t + 2 < T_) ? (t + 2) : (T_ - 1);
        v4f xf[4];
        #pragma unroll
        for (int gt = 0; gt < 4; ++gt) xf[gt] = xg4[tp * 4096 + off[gt]];

        // B fragments: B[k=quad*8+j][n=bL] = H[bL][k]
        const _Float16* hb = &Hl[t & 1][bL][0];
        v8h B0 = *(const v8h*)(hb + quad * 8);
        v8h B1 = *(const v8h*)(hb + 32 + quad * 8);

        v4f G4[4];
        #pragma unroll
        for (int gt = 0; gt < 4; ++gt) {
            v4f d = x0[gt];
            d = __builtin_amdgcn_mfma_f32_16x16x32_f16(A[gt][0], B0, d, 0, 0, 0);
            d = __builtin_amdgcn_mfma_f32_16x16x32_f16(A[gt][1], B1, d, 0, 0, 0);
            G4[gt] = d;
        }

        // lane-local cell update: 4 units x 1 batch
        #pragma unroll
        for (int r = 0; r < 4; ++r) {
            const float I = sigmoidf_(G4[0][r]);
            const float F = sigmoidf_(G4[1][r]);
            const float G = tanhf_(G4[2][r]);
            const float O = sigmoidf_(G4[3][r]);
            c4[r] = F * c4[r] + I * G;
            h4[r] = O * tanhf_(c4[r]);
        }

        // write h (f16) into next-step buffer: units u*16+quad*4+r, row bL
        v4h hp = {(_Float16)h4[0], (_Float16)h4[1], (_Float16)h4[2], (_Float16)h4[3]};
        *(v4h*)(&Hl[(t + 1) & 1][bL][u * 16 + quad * 4]) = hp;   // 8B aligned store

        // h to global (f32), 16B/lane, 64B contiguous per batch row
        *(v4f*)(hbase + t * 64) = h4;

        LDS_BARRIER();                 // all waves' H writes visible; vmem in flight

        #pragma unroll
        for (int gt = 0; gt < 4; ++gt) { x0[gt] = x1[gt]; x1[gt] = xf[gt]; }
    }

    // finals: hT, cT
    *(v4f*)(dout + B_ * T_ * 4 + b * 64 + u * 16 + quad * 4)            = h4;
    *(v4f*)(dout + B_ * T_ * 4 + B_ * 64 + b * 64 + u * 16 + quad * 4)  = c4;
}

// -------------------------------------------------------------------------
// Kernel 3: head (R9 version — hout is (B*T, 64) row-major again).
// -------------------------------------------------------------------------
__global__ __launch_bounds__(256) void head_kernel(
    const float* __restrict__ hout, const float* __restrict__ hw,
    const float* __restrict__ hb, float* __restrict__ out)
{
    const int blk = blockIdx.x;
    const int tid = threadIdx.x;

    __shared__ __align__(16) float hsh[64 * 68];
    __shared__ __align__(16) float wsh[256];
    __shared__ float bsh[4];

    const float4* s4 = (const float4*)(hout + (size_t)blk * 64 * 64);
    float4* d4 = (float4*)hsh;
    for (int q = tid; q < 1024; q += 256) {
        int row = q >> 4, col = q & 15;
        d4[row * 17 + col] = s4[q];
    }
    if (tid < 64) ((float4*)wsh)[tid] = ((const float4*)hw)[tid];
    if (tid < 4)  bsh[tid] = hb[tid];
    __syncthreads();

    const int r = tid >> 2, m = tid & 3;
    const float4* hv = (const float4*)(hsh + r * 68);
    const float4* wv = (const float4*)(wsh + m * 64);
    float acc = bsh[m];
    #pragma unroll
    for (int q = 0; q < 16; ++q) {
        float4 a = hv[q], w = wv[q];
        acc += a.x * w.x + a.y * w.y + a.z * w.z + a.w * w.w;
    }
    out[(size_t)blk * 256 + tid] = sigmoidf_(acc);
}

extern "C" void kernel_launch(void* const* d_in, const int* in_sizes, int n_in,
                              void* d_out, int out_size, void* d_ws, size_t ws_size,
                              hipStream_t stream) {
    const float* pressure = (const float*)d_in[0];
    const float* torque   = (const float*)d_in[1];
    const float* frag     = (const float*)d_in[2];
    const float* pw1 = (const float*)d_in[3];
    const float* pb1 = (const float*)d_in[4];
    const float* pw2 = (const float*)d_in[5];
    const float* pb2 = (const float*)d_in[6];
    const float* tw1 = (const float*)d_in[7];
    const float* tb1 = (const float*)d_in[8];
    const float* tw2 = (const float*)d_in[9];
    const float* tb2 = (const float*)d_in[10];
    const float* fw  = (const float*)d_in[11];
    const float* fb  = (const float*)d_in[12];
    const float* prw = (const float*)d_in[13];
    const float* prb = (const float*)d_in[14];
    const float* Wih = (const float*)d_in[15];
    const float* Whh = (const float*)d_in[16];
    const float* bih = (const float*)d_in[17];
    const float* bhh = (const float*)d_in[18];
    const float* hw  = (const float*)d_in[19];
    const float* hb  = (const float*)d_in[20];

    float* out = (float*)d_out;

    // workspace: xg (16 MB, MFMA C-fragment order) | hout (4 MB, (B,T,64))
    float* xg   = (float*)d_ws;
    float* hout = xg + (size_t)B_ * T_ * 256;

    encoder_kernel<<<B_ * T_ / 4, 256, 0, stream>>>(
        pressure, torque, frag,
        pw1, pb1, pw2, pb2, tw1, tb1, tw2, tb2,
        fw, fb, prw, prb, Wih, bih, bhh, xg);

    lstm_kernel<<<4, 256, 0, stream>>>(xg, Whh, hout, out);

    head_kernel<<<B_ * T_ / 64, 256, 0, stream>>>(hout, hw, hb, out);
}

// Round 13
// 387.466 us; speedup vs baseline: 1.1495x; 1.1495x over previous
//
#include <hip/hip_runtime.h>
#include <math.h>

// Problem constants
#define B_   64
#define T_   256
#define W_   20
#define NP_  6
#define NT_  12
#define CC_  32      // CONV_CH
#define FD_  8       // FRAG_DIM
#define PR_  64      // PROJ

typedef float v2f __attribute__((ext_vector_type(2)));
typedef _Float16 half2_t __attribute__((ext_vector_type(2)));

// Pin a single 32-bit value into a VGPR (opaque def; blocks remat/spill-sink).
#define PINU(x) asm volatile("" : "+v"(x))
// Wave-local LDS ordering: drain LDS ops only; no vmcnt, no barrier.
#define WAVE_SYNC() asm volatile("s_waitcnt lgkmcnt(0)" ::: "memory")

#define H2(u) __builtin_bit_cast(half2_t, (u))

__device__ __forceinline__ unsigned packh2(float a, float b) {
    union { _Float16 h[2]; unsigned u; } cv;
    cv.h[0] = (_Float16)a; cv.h[1] = (_Float16)b;
    return cv.u;
}

// Fast activations via v_rcp_f32 (R11-proven).
__device__ __forceinline__ float sigmoidf_(float x) {
    return __builtin_amdgcn_rcpf(1.0f + __expf(-x));
}
__device__ __forceinline__ float tanhf_(float x) {
    x = fminf(fmaxf(x, -15.0f), 15.0f);
    float e = __expf(2.0f * x);
    return (e - 1.0f) * __builtin_amdgcn_rcpf(e + 1.0f);
}

// -------------------------------------------------------------------------
// Kernel 1: encoders + projection + LSTM input-gate precompute.
// Only change this round: xg stored as PACKED F16 [b][t][unit][4gates]
// (one uint2 per unit) -> halves xg write traffic, lets the LSTM read one
// 8B load per step.
// -------------------------------------------------------------------------
__global__ __launch_bounds__(256, 4) void encoder_kernel(
    const float* __restrict__ pressure, const float* __restrict__ torque,
    const float* __restrict__ frag,
    const float* __restrict__ pw1, const float* __restrict__ pb1,
    const float* __restrict__ pw2, const float* __restrict__ pb2,
    const float* __restrict__ tw1, const float* __restrict__ tb1,
    const float* __restrict__ tw2, const float* __restrict__ tb2,
    const float* __restrict__ fw,  const float* __restrict__ fb,
    const float* __restrict__ prw, const float* __restrict__ prb,
    const float* __restrict__ Wih, const float* __restrict__ bih,
    const float* __restrict__ bhh,
    uint2* __restrict__ xgh)            // (B,T,64) packed 4xf16 gates
{
    const int tid  = threadIdx.x;       // 0..255
    const int wv   = tid >> 6;          // wave 0..3
    const int lane = tid & 63;
    const int bt   = blockIdx.x * 4 + wv;   // window id
    const int b    = bt >> 8;
    const int  o   = lane & 31;
    const bool isp = lane < 32;
    const int  s   = isp ? 0 : 1;       // stream: 0=pressure, 1=torque

    __shared__ unsigned w2p[64 * 49];                    // 12544 B packed conv2 wts
    __shared__ __align__(16) unsigned xwp[4][2][120];    //  3840 B
    __shared__ __align__(16) unsigned h1p[4][2][320];    // 10240 B
    __shared__ __align__(16) float catb4[4][72];
    __shared__ __align__(16) float featsh4[4][64];

    float* catb   = catb4[wv];
    float* featsh = featsh4[wv];

    // ---- stage conv2 weights once per block, packed f16 pairs ----
    for (int idx = tid; idx < 64 * 48; idx += 256) {
        int r = idx / 48, c = idx - r * 48;
        int m = c / 3, k = c - m * 3;
        const float* src = (r < 32) ? (pw2 + r * 96) : (tw2 + (r - 32) * 96);
        w2p[r * 49 + c] = packh2(src[(2 * m) * 3 + k], src[(2 * m + 1) * 3 + k]);
    }

    // ---- zero + stage own window as packed f16 pairs (transposed) ----
    {
        unsigned* xz = &xwp[wv][0][0];
        #pragma unroll
        for (int idx = lane; idx < 240; idx += 64) xz[idx] = 0;
    }
    const float* pin = pressure + (size_t)bt * (W_ * NP_);
    for (int idx = lane; idx < W_ * NP_; idx += 64) {
        int w = idx / NP_, i = idx - w * NP_;
        ((_Float16*)&xwp[wv][0][(i >> 1) * 20 + w])[i & 1] = (_Float16)pin[idx];
    }
    const float* tin = torque + (size_t)bt * (W_ * NT_);
    for (int idx = lane; idx < W_ * NT_; idx += 64) {
        int w = idx / NT_, i = idx - w * NT_;
        ((_Float16*)&xwp[wv][1][(i >> 1) * 20 + w])[i & 1] = (_Float16)tin[idx];
    }
    if (lane < FD_) catb[64 + lane] = fmaxf(frag[b] * fw[lane] + fb[lane], 0.0f);

    // ---- conv1 weights: packed f16 pairs in regs, zero-padded to 6 pairs ----
    unsigned w1p[18];
    {
        const float* w1 = isp ? (pw1 + o * (NP_ * 3)) : (tw1 + o * (NT_ * 3));
        const int npr = isp ? 3 : 6;
        #pragma unroll
        for (int m = 0; m < 6; ++m)
            #pragma unroll
            for (int k = 0; k < 3; ++k)
                w1p[m * 3 + k] = (m < npr)
                    ? packh2(w1[(2 * m) * 3 + k], w1[(2 * m + 1) * 3 + k])
                    : 0u;
    }
    const float bz1 = isp ? pb1[o] : tb1[o];
    const float bz2 = isp ? pb2[o] : tb2[o];
    WAVE_SYNC();

    // ---- conv1: 6 pair-rows x 3 taps x 18 pos, dot2 f16 -> f32 acc ----
    {
        const unsigned* xr = &xwp[wv][s][0];
        float acc[18];
        #pragma unroll
        for (int l = 0; l < 18; ++l) acc[l] = bz1;
        #pragma unroll
        for (int m = 0; m < 6; ++m) {
            uint4 r4[5];
            const uint4* rp = (const uint4*)(xr + m * 20);
            #pragma unroll
            for (int q = 0; q < 5; ++q) r4[q] = rp[q];
            const unsigned* rw = (const unsigned*)r4;
            const half2_t wk0 = H2(w1p[m * 3]), wk1 = H2(w1p[m * 3 + 1]), wk2 = H2(w1p[m * 3 + 2]);
            #pragma unroll
            for (int l = 0; l < 18; ++l) {
                float a = acc[l];
                a = __builtin_amdgcn_fdot2(wk0, H2(rw[l]),     a, false);
                a = __builtin_amdgcn_fdot2(wk1, H2(rw[l + 1]), a, false);
                a = __builtin_amdgcn_fdot2(wk2, H2(rw[l + 2]), a, false);
                acc[l] = a;
            }
        }
        #pragma unroll
        for (int l = 0; l < 18; ++l)
            ((_Float16*)&h1p[wv][s][(o >> 1) * 20 + l])[o & 1] = (_Float16)fmaxf(acc[l], 0.0f);
    }
    __syncthreads();   // the ONE real barrier: w2p (cross-wave) + h1p ready

    // ---- conv2: 16 pair-rows x 3 taps x 16 pos, weights from LDS ----
    {
        const unsigned* hr   = &h1p[wv][s][0];
        const unsigned* wrow = w2p + lane * 49;
        float sacc[16];
        #pragma unroll
        for (int l = 0; l < 16; ++l) sacc[l] = bz2;
        #pragma unroll 4
        for (int m = 0; m < 16; ++m) {
            uint4 r4[5];
            const uint4* rp = (const uint4*)(hr + m * 20);
            #pragma unroll
            for (int q = 0; q < 5; ++q) r4[q] = rp[q];
            const unsigned* rw = (const unsigned*)r4;
            const half2_t wk0 = H2(wrow[m * 3]), wk1 = H2(wrow[m * 3 + 1]), wk2 = H2(wrow[m * 3 + 2]);
            #pragma unroll
            for (int l = 0; l < 16; ++l) {
                float a = sacc[l];
                a = __builtin_amdgcn_fdot2(wk0, H2(rw[l]),     a, false);
                a = __builtin_amdgcn_fdot2(wk1, H2(rw[l + 1]), a, false);
                a = __builtin_amdgcn_fdot2(wk2, H2(rw[l + 2]), a, false);
                sacc[l] = a;
            }
        }
        float m2 = 0.0f;
        #pragma unroll
        for (int l = 0; l < 16; ++l) m2 += fmaxf(sacc[l], 0.0f);
        catb[lane] = m2 * 0.0625f;
    }
    WAVE_SYNC();

    // ---- projection 72 -> 64, relu (f32) ----
    {
        float acc = prb[lane];
        const float4* w4 = (const float4*)(prw + lane * 72);
        const float4* c4 = (const float4*)catb;
        #pragma unroll
        for (int q = 0; q < 18; ++q) {
            float4 w = w4[q], cv = c4[q];
            acc += w.x * cv.x + w.y * cv.y + w.z * cv.z + w.w * cv.w;
        }
        featsh[lane] = fmaxf(acc, 0.0f);
    }
    WAVE_SYNC();

    // ---- xg = feat @ Wih.T + bih + bhh ; packed f16 uint2 store ----
    {
        float4 fr[16];
        const float4* f4 = (const float4*)featsh;
        #pragma unroll
        for (int q = 0; q < 16; ++q) fr[q] = f4[q];
        float acc4[4];
        #pragma unroll
        for (int gi = 0; gi < 4; ++gi) {
            const int g = gi * 64 + lane;        // torch gate order i,f,g,o
            const float4* w4 = (const float4*)(Wih + (size_t)g * 64);
            float acc = bih[g] + bhh[g];
            #pragma unroll
            for (int q = 0; q < 16; ++q) {
                float4 w = w4[q];
                acc += w.x * fr[q].x + w.y * fr[q].y + w.z * fr[q].z + w.w * fr[q].w;
            }
            acc4[gi] = acc;
        }
        uint2 v;
        v.x = packh2(acc4[0], acc4[1]);
        v.y = packh2(acc4[2], acc4[3]);
        xgh[(size_t)bt * 64 + lane] = v;         // 8B/lane, 512B/wave coalesced
    }
}

// -------------------------------------------------------------------------
// Kernel 2: LSTM — single wave per batch element (64 CUs: per-CU xg traffic
// is only 1KB/step, NOT bandwidth-limited — R12's 4-block MFMA version was,
// at 16KB/step/CU). This round kills load-latency exposure: ONE uint2 load
// per step (packed f16 gates), 8-deep ring prefetch (~4400 cyc coverage vs
// ~900 cyc worst-case miss). Weights: 128 pinned f16 pairs (R9-proven).
// -------------------------------------------------------------------------
__global__ __launch_bounds__(64, 1) void lstm_kernel(
    const uint2* __restrict__ xgh,    // (B,T,64) packed 4xf16 gates, bias included
    const float* __restrict__ Whh,    // (256,64)
    float* __restrict__ hout,         // (B, T/4, 64, 4) tq-grouped
    float* __restrict__ dout)         // full output buffer
{
    const int b = blockIdx.x;
    const int j = threadIdx.x;        // hidden unit index

    __shared__ __align__(16) _Float16 hs[64];    // h state in f16 (128 B)

    // 4 Whh rows for unit j (i,f,g,o) as f16 pairs: 4 x 32 uints, pinned
    unsigned wi[32], wf[32], wg[32], wo[32];
    {
        const v2f* ri = (const v2f*)(Whh + (size_t)(j)       * 64);
        const v2f* rf = (const v2f*)(Whh + (size_t)(64  + j) * 64);
        const v2f* rg = (const v2f*)(Whh + (size_t)(128 + j) * 64);
        const v2f* ro = (const v2f*)(Whh + (size_t)(192 + j) * 64);
        #pragma unroll
        for (int q = 0; q < 32; ++q) {
            v2f w;
            w = ri[q]; wi[q] = packh2(w.x, w.y);
            w = rf[q]; wf[q] = packh2(w.x, w.y);
            w = rg[q]; wg[q] = packh2(w.x, w.y);
            w = ro[q]; wo[q] = packh2(w.x, w.y);
        }
        #pragma unroll
        for (int q = 0; q < 32; ++q) { PINU(wi[q]); PINU(wf[q]); PINU(wg[q]); PINU(wo[q]); }
    }

    const uint2* xp = xgh + (size_t)b * T_ * 64 + j;   // stride 64 uint2 per step
    float4* hq4 = (float4*)(hout + (size_t)b * T_ * 64);

    float c = 0.0f;
    float h = 0.0f;
    hs[j] = (_Float16)0.0f;
    WAVE_SYNC();

    // 8-deep ring prefetch of the per-step packed-gate uint2
    uint2 xr[8];
    #pragma unroll
    for (int d = 0; d < 8; ++d) xr[d] = xp[d * 64];

    for (int to = 0; to < T_; to += 8) {
        float4 ha, hb2;
        #pragma unroll
        for (int k = 0; k < 8; ++k) {          // ring slot = k (static)
            const int t  = to + k;
            const uint2 xcur = xr[k];
            int tp = t + 8; if (tp >= T_) tp = T_ - 1;
            xr[k] = xp[tp * 64];               // refill; consumed 8 steps later

            // unpack 4 gate pre-activations
            half2_t xlo = H2(xcur.x), xhi = H2(xcur.y);
            float ai = (float)xlo[0], af = (float)xlo[1];
            float ag = (float)xhi[0], ao = (float)xhi[1];

            // h broadcast: 64 halfs = 128 B = 8 x b128 reads, conflict-free
            uint4 hb[8];
            const uint4* hp = (const uint4*)hs;
            #pragma unroll
            for (int q = 0; q < 8; ++q) hb[q] = hp[q];
            const unsigned* hu = (const unsigned*)hb;

            #pragma unroll
            for (int q = 0; q < 32; ++q) {
                half2_t hq = H2(hu[q]);
                ai = __builtin_amdgcn_fdot2(H2(wi[q]), hq, ai, false);
                af = __builtin_amdgcn_fdot2(H2(wf[q]), hq, af, false);
                ag = __builtin_amdgcn_fdot2(H2(wg[q]), hq, ag, false);
                ao = __builtin_amdgcn_fdot2(H2(wo[q]), hq, ao, false);
            }

            const float I = sigmoidf_(ai);
            const float F = sigmoidf_(af);
            const float G = tanhf_(ag);
            const float O = sigmoidf_(ao);
            c = F * c + I * G;
            h = O * tanhf_(c);

            hs[j] = (_Float16)h;      // ds_write_b16
            WAVE_SYNC();              // lgkmcnt only; vmem stays in flight
            if (k < 4) (&ha.x)[k] = h; else (&hb2.x)[k - 4] = h;
        }
        hq4[(to >> 2) * 64 + j]       = ha;    // 16B/lane, once per 4 steps
        hq4[((to >> 2) + 1) * 64 + j] = hb2;
    }

    dout[B_ * T_ * 4 + b * 64 + j]           = h;   // hT
    dout[B_ * T_ * 4 + B_ * 64 + b * 64 + j] = c;   // cT
}

// -------------------------------------------------------------------------
// Kernel 3: head — tq-grouped hout layout (B,T/4,64,4), R11 version.
// -------------------------------------------------------------------------
__global__ __launch_bounds__(256) void head_kernel(
    const float* __restrict__ hout, const float* __restrict__ hw,
    const float* __restrict__ hb, float* __restrict__ out)
{
    const int blk = blockIdx.x;
    const int tid = threadIdx.x;

    __shared__ __align__(16) float hsh[64 * 68];   // [t_local][unit], row stride 68
    __shared__ __align__(16) float wsh[256];
    __shared__ float bsh[4];

    const float4* s4 = (const float4*)(hout + (size_t)blk * 64 * 64);
    for (int q = tid; q < 1024; q += 256) {
        int tqL = q >> 6;             // local tq group 0..15
        int j   = q & 63;             // unit
        float4 v = s4[q];             // h[j] for t = tqL*4 .. tqL*4+3
        #pragma unroll
        for (int k = 0; k < 4; ++k)
            hsh[(tqL * 4 + k) * 68 + j] = (&v.x)[k];
    }
    if (tid < 64) ((float4*)wsh)[tid] = ((const float4*)hw)[tid];
    if (tid < 4)  bsh[tid] = hb[tid];
    __syncthreads();

    const int r = tid >> 2, m = tid & 3;
    const float4* hv = (const float4*)(hsh + r * 68);
    const float4* wv = (const float4*)(wsh + m * 64);
    float acc = bsh[m];
    #pragma unroll
    for (int q = 0; q < 16; ++q) {
        float4 a = hv[q], w = wv[q];
        acc += a.x * w.x + a.y * w.y + a.z * w.z + a.w * w.w;
    }
    out[(size_t)blk * 256 + tid] = sigmoidf_(acc);
}

extern "C" void kernel_launch(void* const* d_in, const int* in_sizes, int n_in,
                              void* d_out, int out_size, void* d_ws, size_t ws_size,
                              hipStream_t stream) {
    const float* pressure = (const float*)d_in[0];
    const float* torque   = (const float*)d_in[1];
    const float* frag     = (const float*)d_in[2];
    const float* pw1 = (const float*)d_in[3];
    const float* pb1 = (const float*)d_in[4];
    const float* pw2 = (const float*)d_in[5];
    const float* pb2 = (const float*)d_in[6];
    const float* tw1 = (const float*)d_in[7];
    const float* tb1 = (const float*)d_in[8];
    const float* tw2 = (const float*)d_in[9];
    const float* tb2 = (const float*)d_in[10];
    const float* fw  = (const float*)d_in[11];
    const float* fb  = (const float*)d_in[12];
    const float* prw = (const float*)d_in[13];
    const float* prb = (const float*)d_in[14];
    const float* Wih = (const float*)d_in[15];
    const float* Whh = (const float*)d_in[16];
    const float* bih = (const float*)d_in[17];
    const float* bhh = (const float*)d_in[18];
    const float* hw  = (const float*)d_in[19];
    const float* hb  = (const float*)d_in[20];

    float* out = (float*)d_out;

    // workspace: xgh (B*T*64 uint2 = 8 MB, packed f16 gates) | hout (4 MB)
    uint2* xgh  = (uint2*)d_ws;
    float* hout = (float*)((char*)d_ws + (size_t)B_ * T_ * 64 * sizeof(uint2));

    encoder_kernel<<<B_ * T_ / 4, 256, 0, stream>>>(
        pressure, torque, frag,
        pw1, pb1, pw2, pb2, tw1, tb1, tw2, tb2,
        fw, fb, prw, prb, Wih, bih, bhh, xgh);

    lstm_kernel<<<B_, 64, 0, stream>>>(xgh, Whh, hout, out);

    head_kernel<<<B_ * T_ / 64, 256, 0, stream>>>(hout, hw, hb, out);
}